// Round 10
// baseline (208.376 us; speedup 1.0000x reference)
//
#include <hip/hip_runtime.h>

#define B_ 512
#define T_ 512
#define I_ 64
#define H_ 128

// LDS: h ping/pong as bf16[128] (256B each) + dummy dump slots
#define HB0    0
#define HB1    256
#define DUMMY  512
#define LDS_SZ 1536

#define FM(a, x, w) "v_fmac_f32 v" #a ", v" #x ", v" #w "\n\t"
#define SC(n) "v_mul_f32 v" #n ", 0x4038aa3b, v" #n "\n\t"   // *= 2*log2(e)

#define CLOBS \
    "v48","v49","v50","v51","v52","v53","v54","v55","v56","v57","v58","v59", \
    "v60","v61","v62","v63","v64","v65","v66","v67","v68","v69","v70","v71", \
    "v72","v73","v74","v75","v76","v77","v78","v79","v80","v81","v82","v83", \
    "v84","v85","v86","v87","v88","v89","v90","v91","v92","v93","v94","v95", \
    "v96","v97","v98","v99","v100","v101","v102","v103","v104","v105","v106", \
    "v107","v108","v109","v110","v111","v112","v113","v114","v115","v116", \
    "v117","v118","v119","v120","v121","v122","v123","v124","v125","v126", \
    "v127","memory"

// Register map:
//   rec weights (bf16x2, pre-scaled): out r=0..3 -> v80-83/84-87/88-91/92-95
//   proj weights (f32, pre-scaled):   out r=0..3 -> v112-115/116-119/120-123/124-127
//   tok sets: T0 v56-59, T1 v60-63, T2 v64-67, T3 v68-71 (4-deep prefetch)
//   h (8 bf16 = 4 regs): v72-75; accums v48-51; temps v52-55
// Step: 1 ds_read_b128 (h bf16) hidden by 16 f32 proj FMAs; 16 dot2 (2 MAC
// each) for the recurrence; round-9-proven 16-lane DPP reduce + tanh; producer
// cvt_pk to bf16 + ds_write_b16. DPP hazard s_nops as rounds 7-9.
#define RNN_STEP(TA, TB, TC, TD, HRD, HWR)                                    \
    asm volatile(                                                             \
        "ds_read_b128 v[72:75], %1\n\t"                                       \
        "s_waitcnt vmcnt(3)\n\t"                                              \
        "v_fma_f32 v48, v" #TA ", v112, %3\n\t"                               \
        "v_fma_f32 v49, v" #TA ", v116, %4\n\t"                               \
        "v_fma_f32 v50, v" #TA ", v120, %5\n\t"                               \
        "v_fma_f32 v51, v" #TA ", v124, %6\n\t"                               \
        FM(48,TB,113) FM(49,TB,117) FM(50,TB,121) FM(51,TB,125)               \
        FM(48,TC,114) FM(49,TC,118) FM(50,TC,122) FM(51,TC,126)               \
        FM(48,TD,115) FM(49,TD,119) FM(50,TD,123) FM(51,TD,127)               \
        "global_load_dwordx4 v[" #TA ":" #TD "], %0, %9\n\t"                  \
        "v_add_u32 %0, 0x100, %0\n\t"                                         \
        "v_and_b32 %0, 0x1ffff, %0\n\t"                                       \
        "s_waitcnt lgkmcnt(0)\n\t"                                            \
        "v_dot2_f32_bf16 v48, v72, v80, v48\n\t"                              \
        "v_dot2_f32_bf16 v49, v72, v84, v49\n\t"                              \
        "v_dot2_f32_bf16 v50, v72, v88, v50\n\t"                              \
        "v_dot2_f32_bf16 v51, v72, v92, v51\n\t"                              \
        "v_dot2_f32_bf16 v48, v73, v81, v48\n\t"                              \
        "v_dot2_f32_bf16 v49, v73, v85, v49\n\t"                              \
        "v_dot2_f32_bf16 v50, v73, v89, v50\n\t"                              \
        "v_dot2_f32_bf16 v51, v73, v93, v51\n\t"                              \
        "v_dot2_f32_bf16 v48, v74, v82, v48\n\t"                              \
        "v_dot2_f32_bf16 v49, v74, v86, v49\n\t"                              \
        "v_dot2_f32_bf16 v50, v74, v90, v50\n\t"                              \
        "v_dot2_f32_bf16 v51, v74, v94, v51\n\t"                              \
        "v_dot2_f32_bf16 v48, v75, v83, v48\n\t"                              \
        "v_dot2_f32_bf16 v49, v75, v87, v49\n\t"                              \
        "v_dot2_f32_bf16 v50, v75, v91, v50\n\t"                              \
        "v_dot2_f32_bf16 v51, v75, v95, v51\n\t"                              \
        "s_nop 1\n\t"                                                         \
        "v_add_f32 v48, v48, v48 quad_perm:[1,0,3,2] row_mask:0xf bank_mask:0xf\n\t" \
        "v_add_f32 v49, v49, v49 quad_perm:[1,0,3,2] row_mask:0xf bank_mask:0xf\n\t" \
        "v_add_f32 v50, v50, v50 quad_perm:[1,0,3,2] row_mask:0xf bank_mask:0xf\n\t" \
        "v_add_f32 v51, v51, v51 quad_perm:[1,0,3,2] row_mask:0xf bank_mask:0xf\n\t" \
        "v_cndmask_b32 v52, v48, v49, %7\n\t"                                 \
        "v_cndmask_b32 v53, v50, v51, %7\n\t"                                 \
        "s_nop 0\n\t"                                                         \
        "v_add_f32 v52, v52, v52 quad_perm:[2,3,0,1] row_mask:0xf bank_mask:0xf\n\t" \
        "v_add_f32 v53, v53, v53 quad_perm:[2,3,0,1] row_mask:0xf bank_mask:0xf\n\t" \
        "v_cndmask_b32 v54, v52, v53, %8\n\t"                                 \
        "s_nop 1\n\t"                                                         \
        "v_add_f32 v54, v54, v54 row_shl:8 row_mask:0xf bank_mask:0x3\n\t"    \
        "s_nop 1\n\t"                                                         \
        "v_add_f32 v54, v54, v54 row_shl:4 row_mask:0xf bank_mask:0x1\n\t"    \
        "s_nop 1\n\t"                                                         \
        "v_exp_f32 v54, v54\n\t"                                              \
        "s_nop 0\n\t"                                                         \
        "v_add_f32 v54, 1.0, v54\n\t"                                         \
        "v_rcp_f32 v55, v54\n\t"                                              \
        "s_nop 0\n\t"                                                         \
        "v_fma_f32 v54, v55, -2.0, 1.0\n\t"                                   \
        "v_cvt_pk_bf16_f32 v54, v54, v54\n\t"                                 \
        "ds_write_b16 %2, v54\n\t"                                            \
        "s_waitcnt lgkmcnt(0)\n\t"                                            \
        "s_barrier"                                                           \
        : "+v"(voff)                                                          \
        : "v"(HRD), "v"(HWR), "v"(biasA), "v"(biasB), "v"(biasC),             \
          "v"(biasD), "s"(M1), "s"(M2), "s"(sbase)                            \
        : CLOBS)

__global__ __launch_bounds__(512) __attribute__((amdgpu_waves_per_eu(4, 4)))
void rnn_kernel(const float* __restrict__ token,
                const float* __restrict__ W_ih,
                const float* __restrict__ W_hh,
                const float* __restrict__ b_ih,
                const float* __restrict__ b_hh,
                const float* __restrict__ W_lin,
                const float* __restrict__ b_lin,
                float* __restrict__ out)
{
    __shared__ __align__(16) char lds[LDS_SZ];
    const unsigned lb =
        (unsigned)(uintptr_t)(__attribute__((address_space(3))) char*)lds;

    const int tid = threadIdx.x;
    const int e   = tid & 15;         // K-sixteenth
    const int G   = tid >> 4;         // output-quad id 0..31
    const int b   = blockIdx.x;
    const int jb  = 4 * G;

    // ---- rec weights: 4 rows x 8 f32 -> scale -> pack bf16x2 into v80-95 ----
    {
        const float* pWh = W_hh + jb * H_ + e * 8;   // row stride 512B
        asm volatile(
            "global_load_dwordx4 v[48:51], %0, off\n\t"
            "global_load_dwordx4 v[52:55], %0, off offset:16\n\t"
            "global_load_dwordx4 v[56:59], %0, off offset:512\n\t"
            "global_load_dwordx4 v[60:63], %0, off offset:528\n\t"
            "global_load_dwordx4 v[64:67], %0, off offset:1024\n\t"
            "global_load_dwordx4 v[68:71], %0, off offset:1040\n\t"
            "global_load_dwordx4 v[72:75], %0, off offset:1536\n\t"
            "global_load_dwordx4 v[76:79], %0, off offset:1552\n\t"
            "s_waitcnt vmcnt(0)\n\t"
            SC(48) SC(49) SC(50) SC(51) SC(52) SC(53) SC(54) SC(55)
            SC(56) SC(57) SC(58) SC(59) SC(60) SC(61) SC(62) SC(63)
            SC(64) SC(65) SC(66) SC(67) SC(68) SC(69) SC(70) SC(71)
            SC(72) SC(73) SC(74) SC(75) SC(76) SC(77) SC(78) SC(79)
            "v_cvt_pk_bf16_f32 v80, v48, v49\n\t"
            "v_cvt_pk_bf16_f32 v81, v50, v51\n\t"
            "v_cvt_pk_bf16_f32 v82, v52, v53\n\t"
            "v_cvt_pk_bf16_f32 v83, v54, v55\n\t"
            "v_cvt_pk_bf16_f32 v84, v56, v57\n\t"
            "v_cvt_pk_bf16_f32 v85, v58, v59\n\t"
            "v_cvt_pk_bf16_f32 v86, v60, v61\n\t"
            "v_cvt_pk_bf16_f32 v87, v62, v63\n\t"
            "v_cvt_pk_bf16_f32 v88, v64, v65\n\t"
            "v_cvt_pk_bf16_f32 v89, v66, v67\n\t"
            "v_cvt_pk_bf16_f32 v90, v68, v69\n\t"
            "v_cvt_pk_bf16_f32 v91, v70, v71\n\t"
            "v_cvt_pk_bf16_f32 v92, v72, v73\n\t"
            "v_cvt_pk_bf16_f32 v93, v74, v75\n\t"
            "v_cvt_pk_bf16_f32 v94, v76, v77\n\t"
            "v_cvt_pk_bf16_f32 v95, v78, v79\n\t"
            :: "v"(pWh) : CLOBS);
    }
    // ---- proj weights: 4 rows x 4 f32 (f32, scaled) into v112-127 ----
    {
        const float* pWi = W_ih + jb * I_ + e * 4;   // row stride 256B
        asm volatile(
            "global_load_dwordx4 v[112:115], %0, off\n\t"
            "global_load_dwordx4 v[116:119], %0, off offset:256\n\t"
            "global_load_dwordx4 v[120:123], %0, off offset:512\n\t"
            "global_load_dwordx4 v[124:127], %0, off offset:768\n\t"
            "s_waitcnt vmcnt(0)\n\t"
            SC(112) SC(113) SC(114) SC(115) SC(116) SC(117) SC(118) SC(119)
            SC(120) SC(121) SC(122) SC(123) SC(124) SC(125) SC(126) SC(127)
            :: "v"(pWi) : CLOBS);
    }

    // biases pre-scaled by K2/16 (16 lanes each contribute the seed; /16 exact)
    const float k16 = 2.885390081777927f / 16.0f;
    const float biasA = (b_ih[jb + 0] + b_hh[jb + 0]) * k16;
    const float biasB = (b_ih[jb + 1] + b_hh[jb + 1]) * k16;
    const float biasC = (b_ih[jb + 2] + b_hh[jb + 2]) * k16;
    const float biasD = (b_ih[jb + 3] + b_hh[jb + 3]) * k16;
    const unsigned long long M1 = 0xAAAAAAAAAAAAAAAAULL;  // lanes with e&1
    const unsigned long long M2 = 0xCCCCCCCCCCCCCCCCULL;  // lanes with e&2

    // h is LINEAR bf16: h[j] at byte 2j. Lane reads bytes e*16..+15 = h[e*8..+7].
    const int  jsel   = jb + (e & 3);     // writer lanes e<4 finalize jb+e
    const bool writer = (e < 4);
    const unsigned dmy = lb + DUMMY + tid * 2;
    const unsigned hw0 = writer ? (lb + HB1 + jsel * 2) : dmy;  // buf0 -> buf1
    const unsigned hw1 = writer ? (lb + HB0 + jsel * 2) : dmy;  // buf1 -> buf0
    const unsigned hr0 = lb + HB0 + e * 16;
    const unsigned hr1 = lb + HB1 + e * 16;

    const float* tok_row = token + (size_t)b * T_ * I_;
    const unsigned long long sbase = (unsigned long long)(uintptr_t)tok_row;

    // ---- prologue: issue tok(0..3) into T0..T3; zero h buf0 ----
    {
        const unsigned v0 = e * 16;
        asm volatile(
            "global_load_dwordx4 v[56:59], %0, %1\n\t"
            "global_load_dwordx4 v[60:63], %0, %1 offset:256\n\t"
            "global_load_dwordx4 v[64:67], %0, %1 offset:512\n\t"
            "global_load_dwordx4 v[68:71], %0, %1 offset:768\n\t"
            :: "v"(v0), "s"(sbase) : CLOBS);
    }
    unsigned voff = e * 16 + 1024;    // next issue target: tok(4)
    if (tid < H_) *(unsigned short*)(lds + HB0 + tid * 2) = 0;
    asm volatile("s_waitcnt lgkmcnt(0)\n\ts_barrier" ::: "memory");

#pragma unroll 1
    for (int t = 0; t < T_; t += 4) {
        RNN_STEP(56, 57, 58, 59, hr0, hw0);   // t+0: buf0 -> buf1
        RNN_STEP(60, 61, 62, 63, hr1, hw1);   // t+1: buf1 -> buf0
        RNN_STEP(64, 65, 66, 67, hr0, hw0);   // t+2
        RNN_STEP(68, 69, 70, 71, hr1, hw1);   // t+3
    }

    // drain the 4 dangling prefetches (wrapped in-row, harmless)
    asm volatile("s_waitcnt vmcnt(0)" ::: "memory");

    // ---- linear head on h buf0 (512 even steps -> final h in buf0) ----
    if (tid < 64) {
        unsigned u0 = *(const unsigned short*)(lds + HB0 + 2 * tid);
        unsigned u1 = *(const unsigned short*)(lds + HB0 + 2 * (tid + 64));
        float h0 = __uint_as_float(u0 << 16);
        float h1 = __uint_as_float(u1 << 16);
        float p = h0 * W_lin[tid] + h1 * W_lin[tid + 64];
#pragma unroll
        for (int off = 32; off; off >>= 1) p += __shfl_down(p, off);
        if (tid == 0) out[b] = p + b_lin[0];
    }
}

extern "C" void kernel_launch(void* const* d_in, const int* in_sizes, int n_in,
                              void* d_out, int out_size, void* d_ws, size_t ws_size,
                              hipStream_t stream) {
    const float* token = (const float*)d_in[0];
    const float* W_ih  = (const float*)d_in[1];
    const float* W_hh  = (const float*)d_in[2];
    const float* b_ih  = (const float*)d_in[3];
    const float* b_hh  = (const float*)d_in[4];
    const float* W_lin = (const float*)d_in[5];
    const float* b_lin = (const float*)d_in[6];
    float* out = (float*)d_out;

    hipLaunchKernelGGL(rnn_kernel, dim3(B_), dim3(512), 0, stream,
                       token, W_ih, W_hh, b_ih, b_hh, W_lin, b_lin, out);
}